// Round 3
// baseline (207.100 us; speedup 1.0000x reference)
//
#include <hip/hip_runtime.h>
#include <math.h>

// Problem constants (fixed by the reference).
#define M_PTS 16384
#define N_PTS 16384
#define TPB 256

// Spatial binning: 28x28 cells of h=0.375 over [-5.25, 5.25).
// Cutoff: drop terms with exp2(arg) < 2^-40  <=>  sq > 40/cmag.
// For ell=0.1 (cmag=72.13): r_cut = 0.745 <= 2h = 0.75 -> 5x5 neighborhood.
#define NC 28
#define NCELLS (NC * NC)              // 784
#define H 0.375f
#define INV_H (1.0f / 0.375f)
#define ORIG (-5.25f)
#define TCUT 40.0f

#define NPAD_MAX (M_PTS + NCELLS * 63)   // 65776 max padded test slots
#define WAVES_MAX (M_PTS / 64 + NCELLS)  // 1040
#define KITEMS 25
#define ITEMS_MAX (WAVES_MAX * KITEMS)   // 26000
#define MAIN_BLOCKS (ITEMS_MAX / 4)      // 6500 blocks x 4 waves

// ws byte offsets
#define OFF_HDR 0
#define OFF_TRC 256
#define OFF_TEC (OFF_TRC + NCELLS * 4)
#define OFF_TRS (OFF_TEC + NCELLS * 4)
#define OFF_TRCUR (OFF_TRS + NCELLS * 4)
#define OFF_TECUR (OFF_TRCUR + NCELLS * 4)
#define OFF_TRA (OFF_TECUR + NCELLS * 4)       // float4[N]  (16B aligned: 15936)
#define OFF_TRW1 (OFF_TRA + N_PTS * 16)
#define OFF_T4 (OFF_TRW1 + N_PTS * 4)          // float4[NPAD_MAX]
#define WS_NEED (OFF_T4 + (size_t)NPAD_MAX * 16)

__device__ __forceinline__ float fexp2(float x) {
#if __has_builtin(__builtin_amdgcn_exp2f)
    return __builtin_amdgcn_exp2f(x);
#else
    return exp2f(x);
#endif
}

__device__ __forceinline__ void gatomic_fadd(float* p, float v) {
    asm volatile("global_atomic_add_f32 %0, %1, off" :: "v"(p), "v"(v) : "memory");
}

__device__ __forceinline__ int cellco(float v) {
    int c = (int)floorf((v - ORIG) * INV_H);
    return min(NC - 1, max(0, c));
}

// --- preprocessing -----------------------------------------------------------

__global__ void fill_kernel(float4* __restrict__ T4) {
    int i = blockIdx.x * blockDim.x + threadIdx.x;
    if (i < NPAD_MAX)
        T4[i] = make_float4(0.f, 0.f, -3.0e38f, __int_as_float(-1));
}

__global__ void hist_kernel(const float2* __restrict__ Xtr,
                            const float2* __restrict__ Xte,
                            int* __restrict__ trc, int* __restrict__ tec) {
    int i = blockIdx.x * blockDim.x + threadIdx.x;
    if (i >= N_PTS) return;
    float2 t = Xtr[i];
    atomicAdd(&trc[cellco(t.y) * NC + cellco(t.x)], 1);
    float2 x = Xte[i];
    atomicAdd(&tec[cellco(x.y) * NC + cellco(x.x)], 1);
}

__global__ __launch_bounds__(1024) void scan_kernel(
        const int* __restrict__ trc, const int* __restrict__ tec,
        int* __restrict__ trs, int* __restrict__ trcur,
        int* __restrict__ tecur, int* __restrict__ hdr) {
    __shared__ int sc[1024];
    int tid = threadIdx.x;
    // exclusive scan of train counts
    int v = (tid < NCELLS) ? trc[tid] : 0;
    sc[tid] = v; __syncthreads();
    for (int off = 1; off < 1024; off <<= 1) {
        int u = (tid >= off) ? sc[tid - off] : 0;
        __syncthreads();
        sc[tid] += u;
        __syncthreads();
    }
    if (tid < NCELLS) { int e = sc[tid] - v; trs[tid] = e; trcur[tid] = e; }
    __syncthreads();
    // exclusive scan of wave-padded test counts
    int pv = (tid < NCELLS) ? ((tec[tid] + 63) & ~63) : 0;
    sc[tid] = pv; __syncthreads();
    for (int off = 1; off < 1024; off <<= 1) {
        int u = (tid >= off) ? sc[tid - off] : 0;
        __syncthreads();
        sc[tid] += u;
        __syncthreads();
    }
    if (tid < NCELLS) tecur[tid] = sc[tid] - pv;
    if (tid == NCELLS - 1) hdr[0] = sc[tid] / 64;   // waves_pad
}

__global__ void scatter_kernel(const float2* __restrict__ Xtr,
                               const float2* __restrict__ Xte,
                               const float2* __restrict__ alpha,
                               const float* __restrict__ log_ell,
                               const float* __restrict__ log_sf,
                               int* __restrict__ trcur, int* __restrict__ tecur,
                               float4* __restrict__ trA, float* __restrict__ trW1,
                               float4* __restrict__ T4) {
    int i = blockIdx.x * blockDim.x + threadIdx.x;
    if (i >= N_PTS) return;
    float ell = expf(log_ell[0]);
    float sf2 = expf(2.0f * log_sf[0]);
    float c = -0.5f / (ell * ell) * 1.4426950408889634f;  // * log2(e), c < 0

    float2 t = Xtr[i];
    float2 a = alpha[i];
    int ct = cellco(t.y) * NC + cellco(t.x);
    int pt = atomicAdd(&trcur[ct], 1);
    trA[pt] = make_float4(-2.f * c * t.x, -2.f * c * t.y,
                          c * (t.x * t.x + t.y * t.y), sf2 * a.x);
    trW1[pt] = sf2 * a.y;

    float2 x = Xte[i];
    int cx = cellco(x.y) * NC + cellco(x.x);
    int px = atomicAdd(&tecur[cx], 1);
    T4[px] = make_float4(x.x, x.y, c * (x.x * x.x + x.y * x.y), __int_as_float(i));
}

// --- main sparse kernel ------------------------------------------------------
// Wave item = (test-wave tw, neighbor-cell k of 5x5). Waves are cell-uniform
// by padding; train list of the target cell is scanned with wave-uniform
// loads; exp skipped wave-coherently via ballot.
__global__ __launch_bounds__(TPB, 8) void gp_sparse(
        const float4* __restrict__ T4, const float4* __restrict__ trA,
        const float* __restrict__ trW1, const int* __restrict__ trs,
        const int* __restrict__ trc, const int* __restrict__ hdr,
        const float* __restrict__ log_ell, float* __restrict__ out) {
    const int wave = (blockIdx.x << 2) + (threadIdx.x >> 6);
    const int lane = threadIdx.x & 63;
    const int tw = wave / KITEMS;
    const int k = wave - tw * KITEMS;
    if (tw >= hdr[0]) return;

    const float ell = expf(log_ell[0]);
    const float cmag = 0.5f / (ell * ell) * 1.4426950408889634f;
    const bool fb = (TCUT / cmag) > (4.0f * H * H);  // r_cut > 2h: 5x5 insufficient

    float4 tp = T4[tw * 64 + lane];
    const float x = tp.x, y = tp.y, b = tp.z;       // b = c*|x|^2 (-3e38 for dummy)
    const int oidx = __float_as_int(tp.w);

    int js, je;
    if (fb) {
        if (k != 12) return;   // correctness fallback: scan everything
        js = 0; je = N_PTS;
    } else {
        int cx = __builtin_amdgcn_readfirstlane(cellco(x));  // lane 0 is always real
        int cy = __builtin_amdgcn_readfirstlane(cellco(y));
        int tcx = cx + (k % 5) - 2;
        int tcy = cy + (k / 5) - 2;
        if (tcx < 0 || tcx >= NC || tcy < 0 || tcy >= NC) return;
        int cid = tcy * NC + tcx;
        js = trs[cid];
        je = js + trc[cid];
    }

    float a0 = 0.f, a1 = 0.f;
#pragma unroll 2
    for (int j = js; j < je; ++j) {
        float4 tv = trA[j];                          // wave-uniform
        float t = fmaf(tv.x, x, fmaf(tv.y, y, b + tv.z));  // = c*sq (<=0)
        if (__ballot(t > -TCUT) != 0ull) {
            float e = fexp2(t);                      // exp2(c*sq); 0 for far/dummy
            a0 = fmaf(e, tv.w, a0);
            a1 = fmaf(e, trW1[j], a1);
        }
    }

    if (oidx >= 0 && ((a0 != 0.f) || (a1 != 0.f))) {
        gatomic_fadd(&out[2 * oidx], a0);
        gatomic_fadd(&out[2 * oidx + 1], a1);
    }
}

// --- dense fallback (ws too small) ------------------------------------------
__global__ __launch_bounds__(TPB, 8) void gp_dense(
        const float2* __restrict__ Xte, const float2* __restrict__ Xtr,
        const float2* __restrict__ alpha, const float* __restrict__ log_ell,
        const float* __restrict__ log_sf, float* __restrict__ out) {
    __shared__ float4 sSt[128];
    __shared__ float sA1[128];
    const int tid = threadIdx.x;
    const float ell = expf(log_ell[0]);
    const float c = -0.5f / (ell * ell) * 1.4426950408889634f;
    const int j0 = blockIdx.y * 128;
    if (tid < 128) {
        const float sf2 = expf(2.0f * log_sf[0]);
        float2 t = Xtr[j0 + tid];
        float2 a = alpha[j0 + tid];
        sSt[tid] = make_float4(-2.f * c * t.x, -2.f * c * t.y,
                               c * (t.x * t.x + t.y * t.y), sf2 * a.x);
        sA1[tid] = sf2 * a.y;
    }
    const int base = blockIdx.x * (TPB * 4) + tid;
    float2 x0 = Xte[base], x1 = Xte[base + TPB];
    float2 x2 = Xte[base + 2 * TPB], x3 = Xte[base + 3 * TPB];
    const float b0 = c * (x0.x * x0.x + x0.y * x0.y);
    const float b1 = c * (x1.x * x1.x + x1.y * x1.y);
    const float b2 = c * (x2.x * x2.x + x2.y * x2.y);
    const float b3 = c * (x3.x * x3.x + x3.y * x3.y);
    __syncthreads();
    float a00 = 0.f, a01 = 0.f, a10 = 0.f, a11 = 0.f;
    float a20 = 0.f, a21 = 0.f, a30 = 0.f, a31 = 0.f;
#pragma unroll 2
    for (int j = 0; j < 128; ++j) {
        float4 s = sSt[j];
        float w1 = sA1[j];
        float t0 = fminf(fmaf(s.x, x0.x, fmaf(s.y, x0.y, b0 + s.z)), 0.f);
        float t1 = fminf(fmaf(s.x, x1.x, fmaf(s.y, x1.y, b1 + s.z)), 0.f);
        float t2 = fminf(fmaf(s.x, x2.x, fmaf(s.y, x2.y, b2 + s.z)), 0.f);
        float t3 = fminf(fmaf(s.x, x3.x, fmaf(s.y, x3.y, b3 + s.z)), 0.f);
        float e0 = fexp2(t0), e1 = fexp2(t1), e2 = fexp2(t2), e3 = fexp2(t3);
        a00 = fmaf(e0, s.w, a00); a01 = fmaf(e0, w1, a01);
        a10 = fmaf(e1, s.w, a10); a11 = fmaf(e1, w1, a11);
        a20 = fmaf(e2, s.w, a20); a21 = fmaf(e2, w1, a21);
        a30 = fmaf(e3, s.w, a30); a31 = fmaf(e3, w1, a31);
    }
    gatomic_fadd(&out[2 * base], a00);             gatomic_fadd(&out[2 * base + 1], a01);
    gatomic_fadd(&out[2 * (base + TPB)], a10);      gatomic_fadd(&out[2 * (base + TPB) + 1], a11);
    gatomic_fadd(&out[2 * (base + 2 * TPB)], a20);  gatomic_fadd(&out[2 * (base + 2 * TPB) + 1], a21);
    gatomic_fadd(&out[2 * (base + 3 * TPB)], a30);  gatomic_fadd(&out[2 * (base + 3 * TPB) + 1], a31);
}

extern "C" void kernel_launch(void* const* d_in, const int* in_sizes, int n_in,
                              void* d_out, int out_size, void* d_ws, size_t ws_size,
                              hipStream_t stream) {
    const float2* Xte = (const float2*)d_in[0];
    const float2* Xtr = (const float2*)d_in[1];
    const float2* alpha = (const float2*)d_in[2];
    const float* log_ell = (const float*)d_in[3];
    const float* log_sf = (const float*)d_in[4];
    float* out = (float*)d_out;

    hipMemsetAsync(out, 0, (size_t)out_size * sizeof(float), stream);

    if (ws_size >= WS_NEED) {
        char* ws = (char*)d_ws;
        int* hdr = (int*)(ws + OFF_HDR);
        int* trc = (int*)(ws + OFF_TRC);
        int* tec = (int*)(ws + OFF_TEC);
        int* trs = (int*)(ws + OFF_TRS);
        int* trcur = (int*)(ws + OFF_TRCUR);
        int* tecur = (int*)(ws + OFF_TECUR);
        float4* trA = (float4*)(ws + OFF_TRA);
        float* trW1 = (float*)(ws + OFF_TRW1);
        float4* T4 = (float4*)(ws + OFF_T4);

        // zero both histogram arrays (contiguous)
        hipMemsetAsync(trc, 0, NCELLS * 2 * sizeof(int), stream);
        fill_kernel<<<(NPAD_MAX + TPB - 1) / TPB, TPB, 0, stream>>>(T4);
        hist_kernel<<<N_PTS / TPB, TPB, 0, stream>>>(Xtr, Xte, trc, tec);
        scan_kernel<<<1, 1024, 0, stream>>>(trc, tec, trs, trcur, tecur, hdr);
        scatter_kernel<<<N_PTS / TPB, TPB, 0, stream>>>(Xtr, Xte, alpha, log_ell,
                                                        log_sf, trcur, tecur,
                                                        trA, trW1, T4);
        gp_sparse<<<MAIN_BLOCKS, TPB, 0, stream>>>(T4, trA, trW1, trs, trc, hdr,
                                                   log_ell, out);
    } else {
        dim3 grid(M_PTS / (TPB * 4), N_PTS / 128);
        gp_dense<<<grid, TPB, 0, stream>>>(Xte, Xtr, alpha, log_ell, log_sf, out);
    }
}

// Round 4
// 162.053 us; speedup vs baseline: 1.2780x; 1.2780x over previous
//
#include <hip/hip_runtime.h>
#include <math.h>

// Problem constants (fixed by the reference).
#define M_PTS 16384
#define N_PTS 16384

// Spatial binning: 28x28 cells of h=0.375 over [-5.25, 5.25).
// Drop terms with exp2(arg) < 2^-40  <=>  sq > TCUT/cmag.
// ell=0.1 -> cmag=72.13 -> r_cut=0.745 <= 2h=0.75 -> 5x5 neighborhood exact
// (to 1e-7 abs). Runtime check falls back to full scan if ell too large.
#define NC 28
#define NCELLS (NC * NC)                 // 784
#define H 0.375f
#define INV_H (1.0f / 0.375f)
#define ORIG (-5.25f)
#define TCUT 40.0f

#define TRA_PAD_MAX (N_PTS + 4 * NCELLS)     // 19520 train slots (cells pad->4)
#define NPAD_MAX (M_PTS + NCELLS * 63)       // 65776 test slots (cells pad->64)
#define MAXWAVES 1040

// ws byte offsets
#define OFF_HDR 0                            // hdr[0]=test waves, hdr[1]=train total
#define OFF_TRC 256
#define OFF_TEC (OFF_TRC + NCELLS * 4)       // memset covers TRC+TEC (6272 B)
#define OFF_TRS4 (OFF_TEC + NCELLS * 4)      // (NCELLS+1) ints, 4-aligned starts
#define OFF_TRCUR 9728
#define OFF_TECUR (OFF_TRCUR + NCELLS * 4)
#define OFF_TRA 16000                        // float4[TRA_PAD_MAX], 16B aligned
#define OFF_TRW1 (OFF_TRA + TRA_PAD_MAX * 16)
#define OFF_T4 (OFF_TRW1 + TRA_PAD_MAX * 4 + 12544)  // 16B aligned
#define WS_NEED (OFF_T4 + (size_t)NPAD_MAX * 16)

__device__ __forceinline__ float fexp2(float x) {
#if __has_builtin(__builtin_amdgcn_exp2f)
    return __builtin_amdgcn_exp2f(x);
#else
    return exp2f(x);
#endif
}

__device__ __forceinline__ void gatomic_fadd(float* p, float v) {
    asm volatile("global_atomic_add_f32 %0, %1, off" :: "v"(p), "v"(v) : "memory");
}

__device__ __forceinline__ int cellco(float v) {
    int c = (int)floorf((v - ORIG) * INV_H);
    return min(NC - 1, max(0, c));
}

// --- d2: fill dummies, zero out, histogram both point sets -------------------
__global__ void fillhist_kernel(const float2* __restrict__ Xtr,
                                const float2* __restrict__ Xte,
                                float4* __restrict__ trA, float* __restrict__ trW1,
                                float4* __restrict__ T4, float2* __restrict__ out2,
                                int* __restrict__ trc, int* __restrict__ tec) {
    int i = blockIdx.x * blockDim.x + threadIdx.x;
    if (i < TRA_PAD_MAX) {
        trA[i] = make_float4(0.f, 0.f, -1.0e30f, 0.f);  // exp2 -> 0, weight 0
        trW1[i] = 0.f;
    }
    if (i < NPAD_MAX)
        T4[i] = make_float4(0.f, 0.f, -1.0e30f, __int_as_float(-1));
    if (i < M_PTS)
        out2[i] = make_float2(0.f, 0.f);
    if (i < N_PTS) {
        float2 t = Xtr[i];
        atomicAdd(&trc[cellco(t.y) * NC + cellco(t.x)], 1);
        float2 x = Xte[i];
        atomicAdd(&tec[cellco(x.y) * NC + cellco(x.x)], 1);
    }
}

// --- d3: prefix sums (padded) ------------------------------------------------
__global__ __launch_bounds__(1024) void scan_kernel(
        const int* __restrict__ trc, const int* __restrict__ tec,
        int* __restrict__ trs4, int* __restrict__ trcur,
        int* __restrict__ tecur, int* __restrict__ hdr) {
    __shared__ int sc[1024];
    int tid = threadIdx.x;
    // train counts padded to multiple of 4
    int v = (tid < NCELLS) ? ((trc[tid] + 3) & ~3) : 0;
    sc[tid] = v; __syncthreads();
    for (int off = 1; off < 1024; off <<= 1) {
        int u = (tid >= off) ? sc[tid - off] : 0;
        __syncthreads();
        sc[tid] += u;
        __syncthreads();
    }
    if (tid < NCELLS) { int e = sc[tid] - v; trs4[tid] = e; trcur[tid] = e; }
    if (tid == NCELLS - 1) { trs4[NCELLS] = sc[tid]; hdr[1] = sc[tid]; }
    __syncthreads();
    // test counts padded to multiple of 64 (wave-uniform cells)
    int pv = (tid < NCELLS) ? ((tec[tid] + 63) & ~63) : 0;
    sc[tid] = pv; __syncthreads();
    for (int off = 1; off < 1024; off <<= 1) {
        int u = (tid >= off) ? sc[tid - off] : 0;
        __syncthreads();
        sc[tid] += u;
        __syncthreads();
    }
    if (tid < NCELLS) tecur[tid] = sc[tid] - pv;
    if (tid == NCELLS - 1) hdr[0] = sc[tid] >> 6;
}

// --- d4: scatter sorted/staged data -----------------------------------------
__global__ void scatter_kernel(const float2* __restrict__ Xtr,
                               const float2* __restrict__ Xte,
                               const float2* __restrict__ alpha,
                               const float* __restrict__ log_ell,
                               const float* __restrict__ log_sf,
                               int* __restrict__ trcur, int* __restrict__ tecur,
                               float4* __restrict__ trA, float* __restrict__ trW1,
                               float4* __restrict__ T4) {
    int i = blockIdx.x * blockDim.x + threadIdx.x;
    if (i >= N_PTS) return;
    float ell = expf(log_ell[0]);
    float sf2 = expf(2.0f * log_sf[0]);
    float c = -0.5f / (ell * ell) * 1.4426950408889634f;  // * log2(e), c < 0

    float2 t = Xtr[i];
    float2 a = alpha[i];
    int ct = cellco(t.y) * NC + cellco(t.x);
    int pt = atomicAdd(&trcur[ct], 1);
    trA[pt] = make_float4(-2.f * c * t.x, -2.f * c * t.y,
                          c * (t.x * t.x + t.y * t.y), sf2 * a.x);
    trW1[pt] = sf2 * a.y;

    float2 x = Xte[i];
    int cx = cellco(x.y) * NC + cellco(x.x);
    int px = atomicAdd(&tecur[cx], 1);
    T4[px] = make_float4(x.x, x.y, c * (x.x * x.x + x.y * x.y), __int_as_float(i));
}

// --- d5: main sparse kernel --------------------------------------------------
// Block (row k=0..4, test-wave tw). 8 waves = 8 phases stride the contiguous
// 5-cell row window [js,je). Inner loop is branch-free (exp2 underflow kills
// far/dummy terms). LDS-reduce 8 phases, then <=2 atomics per lane.
__global__ __launch_bounds__(512) void gp_rows(
        const float4* __restrict__ T4, const float4* __restrict__ trA,
        const float* __restrict__ trW1, const int* __restrict__ trs4,
        const int* __restrict__ hdr, const float* __restrict__ log_ell,
        float* __restrict__ out) {
    const int tw = blockIdx.y;
    if (tw >= hdr[0]) return;            // uniform: no barrier yet
    const int k = blockIdx.x;            // 0..4 row offset
    const int p = threadIdx.x >> 6;      // phase 0..7
    const int lane = threadIdx.x & 63;

    __shared__ float2 red[8][64];

    const float ell = expf(log_ell[0]);
    const float cmag = 0.5f / (ell * ell) * 1.4426950408889634f;
    const bool fb = (TCUT / cmag) > (4.0f * H * H);  // r_cut > 2h

    float4 tp = T4[tw * 64 + lane];
    const float x = tp.x, y = tp.y, b = tp.z;        // b = c*|x|^2 (-1e30 pad)
    const int oidx = __float_as_int(tp.w);

    int js = 0, je = 0;
    if (fb) {
        if (k == 2) je = hdr[1];         // full scan (dummies are safe)
    } else {
        int cx = __builtin_amdgcn_readfirstlane(cellco(x));  // lane 0 is real
        int cy = __builtin_amdgcn_readfirstlane(cellco(y));
        int tcy = cy + k - 2;
        if (tcy >= 0 && tcy < NC) {
            int cl = tcy * NC + max(0, cx - 2);
            int cr = tcy * NC + min(NC - 1, cx + 2);
            js = trs4[cl];
            je = trs4[cr + 1];
        }
    }

    float a0 = 0.f, a1 = 0.f;
    for (int j = js + (p << 2); j < je; j += 32) {
        float4 t0 = trA[j];
        float4 t1 = trA[j + 1];
        float4 t2 = trA[j + 2];
        float4 t3 = trA[j + 3];
        float4 wv = *(const float4*)(trW1 + j);
        float e0 = fexp2(fmaf(t0.x, x, fmaf(t0.y, y, b + t0.z)));
        float e1 = fexp2(fmaf(t1.x, x, fmaf(t1.y, y, b + t1.z)));
        float e2 = fexp2(fmaf(t2.x, x, fmaf(t2.y, y, b + t2.z)));
        float e3 = fexp2(fmaf(t3.x, x, fmaf(t3.y, y, b + t3.z)));
        a0 = fmaf(e0, t0.w, a0); a1 = fmaf(e0, wv.x, a1);
        a0 = fmaf(e1, t1.w, a0); a1 = fmaf(e1, wv.y, a1);
        a0 = fmaf(e2, t2.w, a0); a1 = fmaf(e2, wv.z, a1);
        a0 = fmaf(e3, t3.w, a0); a1 = fmaf(e3, wv.w, a1);
    }

    red[p][lane] = make_float2(a0, a1);
    __syncthreads();
    if (p == 0) {
        float s0 = 0.f, s1 = 0.f;
#pragma unroll
        for (int q = 0; q < 8; ++q) {
            float2 v = red[q][lane];
            s0 += v.x; s1 += v.y;
        }
        if (oidx >= 0 && (s0 != 0.f || s1 != 0.f)) {
            gatomic_fadd(&out[2 * oidx], s0);
            gatomic_fadd(&out[2 * oidx + 1], s1);
        }
    }
}

// --- dense fallback (ws too small) ------------------------------------------
__global__ __launch_bounds__(256, 8) void gp_dense(
        const float2* __restrict__ Xte, const float2* __restrict__ Xtr,
        const float2* __restrict__ alpha, const float* __restrict__ log_ell,
        const float* __restrict__ log_sf, float* __restrict__ out) {
    __shared__ float4 sSt[128];
    __shared__ float sA1[128];
    const int tid = threadIdx.x;
    const float ell = expf(log_ell[0]);
    const float c = -0.5f / (ell * ell) * 1.4426950408889634f;
    const int j0 = blockIdx.y * 128;
    if (tid < 128) {
        const float sf2 = expf(2.0f * log_sf[0]);
        float2 t = Xtr[j0 + tid];
        float2 a = alpha[j0 + tid];
        sSt[tid] = make_float4(-2.f * c * t.x, -2.f * c * t.y,
                               c * (t.x * t.x + t.y * t.y), sf2 * a.x);
        sA1[tid] = sf2 * a.y;
    }
    const int base = blockIdx.x * 1024 + tid;
    float2 x0 = Xte[base], x1 = Xte[base + 256];
    float2 x2 = Xte[base + 512], x3 = Xte[base + 768];
    const float b0 = c * (x0.x * x0.x + x0.y * x0.y);
    const float b1 = c * (x1.x * x1.x + x1.y * x1.y);
    const float b2 = c * (x2.x * x2.x + x2.y * x2.y);
    const float b3 = c * (x3.x * x3.x + x3.y * x3.y);
    __syncthreads();
    float a00 = 0.f, a01 = 0.f, a10 = 0.f, a11 = 0.f;
    float a20 = 0.f, a21 = 0.f, a30 = 0.f, a31 = 0.f;
#pragma unroll 2
    for (int j = 0; j < 128; ++j) {
        float4 s = sSt[j];
        float w1 = sA1[j];
        float e0 = fexp2(fminf(fmaf(s.x, x0.x, fmaf(s.y, x0.y, b0 + s.z)), 0.f));
        float e1 = fexp2(fminf(fmaf(s.x, x1.x, fmaf(s.y, x1.y, b1 + s.z)), 0.f));
        float e2 = fexp2(fminf(fmaf(s.x, x2.x, fmaf(s.y, x2.y, b2 + s.z)), 0.f));
        float e3 = fexp2(fminf(fmaf(s.x, x3.x, fmaf(s.y, x3.y, b3 + s.z)), 0.f));
        a00 = fmaf(e0, s.w, a00); a01 = fmaf(e0, w1, a01);
        a10 = fmaf(e1, s.w, a10); a11 = fmaf(e1, w1, a11);
        a20 = fmaf(e2, s.w, a20); a21 = fmaf(e2, w1, a21);
        a30 = fmaf(e3, s.w, a30); a31 = fmaf(e3, w1, a31);
    }
    gatomic_fadd(&out[2 * base], a00);            gatomic_fadd(&out[2 * base + 1], a01);
    gatomic_fadd(&out[2 * (base + 256)], a10);    gatomic_fadd(&out[2 * (base + 256) + 1], a11);
    gatomic_fadd(&out[2 * (base + 512)], a20);    gatomic_fadd(&out[2 * (base + 512) + 1], a21);
    gatomic_fadd(&out[2 * (base + 768)], a30);    gatomic_fadd(&out[2 * (base + 768) + 1], a31);
}

extern "C" void kernel_launch(void* const* d_in, const int* in_sizes, int n_in,
                              void* d_out, int out_size, void* d_ws, size_t ws_size,
                              hipStream_t stream) {
    const float2* Xte = (const float2*)d_in[0];
    const float2* Xtr = (const float2*)d_in[1];
    const float2* alpha = (const float2*)d_in[2];
    const float* log_ell = (const float*)d_in[3];
    const float* log_sf = (const float*)d_in[4];
    float* out = (float*)d_out;

    if (ws_size >= WS_NEED) {
        char* ws = (char*)d_ws;
        int* hdr = (int*)(ws + OFF_HDR);
        int* trc = (int*)(ws + OFF_TRC);
        int* tec = (int*)(ws + OFF_TEC);
        int* trs4 = (int*)(ws + OFF_TRS4);
        int* trcur = (int*)(ws + OFF_TRCUR);
        int* tecur = (int*)(ws + OFF_TECUR);
        float4* trA = (float4*)(ws + OFF_TRA);
        float* trW1 = (float*)(ws + OFF_TRW1);
        float4* T4 = (float4*)(ws + OFF_T4);

        hipMemsetAsync(trc, 0, NCELLS * 2 * sizeof(int), stream);   // trc+tec
        fillhist_kernel<<<(NPAD_MAX + 255) / 256, 256, 0, stream>>>(
            Xtr, Xte, trA, trW1, T4, (float2*)out, trc, tec);
        scan_kernel<<<1, 1024, 0, stream>>>(trc, tec, trs4, trcur, tecur, hdr);
        scatter_kernel<<<N_PTS / 256, 256, 0, stream>>>(
            Xtr, Xte, alpha, log_ell, log_sf, trcur, tecur, trA, trW1, T4);
        dim3 grid(5, MAXWAVES);
        gp_rows<<<grid, 512, 0, stream>>>(T4, trA, trW1, trs4, hdr, log_ell, out);
    } else {
        hipMemsetAsync(out, 0, (size_t)out_size * sizeof(float), stream);
        dim3 grid(M_PTS / 1024, N_PTS / 128);
        gp_dense<<<grid, 256, 0, stream>>>(Xte, Xtr, alpha, log_ell, log_sf, out);
    }
}

// Round 5
// 130.370 us; speedup vs baseline: 1.5886x; 1.2430x over previous
//
#include <hip/hip_runtime.h>
#include <math.h>

// Problem constants (fixed by the reference).
#define M_PTS 16384
#define N_PTS 16384

// Spatial binning: 28x28 cells of h=0.375 over [-5.25, 5.25).
// Drop terms with exp2(arg) < 2^-40  <=>  sq > TCUT/cmag.
// ell=0.1 -> cmag=72.13 -> r_cut=0.745 <= 2h=0.75 -> 5x5 neighborhood exact
// (to ~1e-7 abs). Runtime check falls back to full scan if ell too large.
#define NC 28
#define NCELLS (NC * NC)                 // 784
#define H 0.375f
#define INV_H (1.0f / 0.375f)
#define ORIG (-5.25f)
#define TCUT 40.0f

#define CHUNK 1024                       // LDS-staged trains per chunk
#define MAXWAVES 1040                    // <= M/64 + NCELLS padded test waves
#define TRA_PAD_MAX (N_PTS + 4 * NCELLS) // 19520 (cells padded to x4)
#define NPAD_MAX (M_PTS + NCELLS * 63)   // 65776 padded test slots

// ws byte offsets
#define OFF_HDR 0                        // hdr[0]=test waves, hdr[1]=train total
#define OFF_TRS4 64                      // (NCELLS+1) ints
#define OFF_TRCUR (OFF_TRS4 + 3200)
#define OFF_TECUR (OFF_TRCUR + 3200)
#define OFF_TRA 16384                    // float4[TRA_PAD_MAX], 16B aligned
#define OFF_TRW1 (OFF_TRA + TRA_PAD_MAX * 16)          // 328704
#define OFF_T4 (OFF_TRW1 + TRA_PAD_MAX * 4)            // 406784, 16B aligned
#define WS_NEED (OFF_T4 + (size_t)NPAD_MAX * 16)       // ~1.46 MB

__device__ __forceinline__ float fexp2(float x) {
#if __has_builtin(__builtin_amdgcn_exp2f)
    return __builtin_amdgcn_exp2f(x);
#else
    return exp2f(x);
#endif
}

__device__ __forceinline__ void gatomic_fadd(float* p, float v) {
    asm volatile("global_atomic_add_f32 %0, %1, off" :: "v"(p), "v"(v) : "memory");
}

__device__ __forceinline__ int cellco(float v) {
    int c = (int)floorf((v - ORIG) * INV_H);
    return min(NC - 1, max(0, c));
}

// --- d1: histogram + prefix scans, all in one single-block kernel ------------
__global__ __launch_bounds__(1024) void hist_scan_kernel(
        const float2* __restrict__ Xtr, const float2* __restrict__ Xte,
        int* __restrict__ trs4, int* __restrict__ trcur,
        int* __restrict__ tecur, int* __restrict__ hdr) {
    __shared__ int h[2 * NCELLS];
    __shared__ int sc[1024];
    const int tid = threadIdx.x;
    for (int i = tid; i < 2 * NCELLS; i += 1024) h[i] = 0;
    __syncthreads();
    for (int i = tid; i < N_PTS; i += 1024) {
        float2 t = Xtr[i];
        atomicAdd(&h[cellco(t.y) * NC + cellco(t.x)], 1);
        float2 x = Xte[i];
        atomicAdd(&h[NCELLS + cellco(x.y) * NC + cellco(x.x)], 1);
    }
    __syncthreads();
    // train counts padded to x4
    int v = (tid < NCELLS) ? ((h[tid] + 3) & ~3) : 0;
    sc[tid] = v; __syncthreads();
    for (int off = 1; off < 1024; off <<= 1) {
        int u = (tid >= off) ? sc[tid - off] : 0;
        __syncthreads();
        sc[tid] += u;
        __syncthreads();
    }
    if (tid < NCELLS) { int e = sc[tid] - v; trs4[tid] = e; trcur[tid] = e; }
    if (tid == NCELLS - 1) { trs4[NCELLS] = sc[tid]; hdr[1] = sc[tid]; }
    __syncthreads();
    // test counts padded to x64 (wave-uniform cells)
    int pv = (tid < NCELLS) ? ((h[NCELLS + tid] + 63) & ~63) : 0;
    sc[tid] = pv; __syncthreads();
    for (int off = 1; off < 1024; off <<= 1) {
        int u = (tid >= off) ? sc[tid - off] : 0;
        __syncthreads();
        sc[tid] += u;
        __syncthreads();
    }
    if (tid < NCELLS) tecur[tid] = sc[tid] - pv;
    if (tid == NCELLS - 1) hdr[0] = sc[tid] >> 6;
}

// --- d2: scatter sorted/staged data -----------------------------------------
// trA[p] = (-2c*t0, -2c*t1, c*|t|^2, sf2*a0), trW1[p] = sf2*a1.
// T4[p] = (x, y, c*|x|^2, idx+1 as float-bits): idx+1 so that poison (0xAA..,
// negative int) AND zero ws both decode as invalid.
__global__ void scatter_kernel(const float2* __restrict__ Xtr,
                               const float2* __restrict__ Xte,
                               const float2* __restrict__ alpha,
                               const float* __restrict__ log_ell,
                               const float* __restrict__ log_sf,
                               int* __restrict__ trcur, int* __restrict__ tecur,
                               float4* __restrict__ trA, float* __restrict__ trW1,
                               float4* __restrict__ T4) {
    int i = blockIdx.x * blockDim.x + threadIdx.x;
    if (i >= N_PTS) return;
    float ell = expf(log_ell[0]);
    float sf2 = expf(2.0f * log_sf[0]);
    float c = -0.5f / (ell * ell) * 1.4426950408889634f;  // * log2(e), c < 0

    float2 t = Xtr[i];
    float2 a = alpha[i];
    int ct = cellco(t.y) * NC + cellco(t.x);
    int pt = atomicAdd(&trcur[ct], 1);
    trA[pt] = make_float4(-2.f * c * t.x, -2.f * c * t.y,
                          c * (t.x * t.x + t.y * t.y), sf2 * a.x);
    trW1[pt] = sf2 * a.y;

    float2 x = Xte[i];
    int cx = cellco(x.y) * NC + cellco(x.x);
    int px = atomicAdd(&tecur[cx], 1);
    T4[px] = make_float4(x.x, x.y, c * (x.x * x.x + x.y * x.y),
                         __int_as_float(i + 1));
}

// --- d3: main kernel ---------------------------------------------------------
// Block = one padded test wave (cell-uniform). 8 waves cooperatively stage the
// wave's whole 5x5 window (5 contiguous row-spans) into LDS, then each wave
// computes an interleaved 1/8 of the quads with branch-free exp2 (LDS reads
// are wave-uniform broadcasts -> pipelined fine-grained lgkmcnt, unlike the
// SMEM s_load/lgkmcnt(0) serialization of the previous version). One block
// owns each test point -> plain float2 stores, no atomics, no out-zeroing.
__global__ __launch_bounds__(512, 8) void gp_main(
        const float4* __restrict__ T4, const float4* __restrict__ trA,
        const float* __restrict__ trW1, const int* __restrict__ trs4,
        const int* __restrict__ hdr, const float* __restrict__ log_ell,
        float2* __restrict__ out2) {
    const int tw = blockIdx.x;
    if (tw >= hdr[0]) return;            // uniform for the whole block

    __shared__ float4 sA[CHUNK];                       // 16 KB
    __shared__ __align__(16) float sW[CHUNK];          // 4 KB
    __shared__ float2 red[8][64];                      // 4 KB
    __shared__ int sS[5];                              // span starts
    __shared__ int sP[6];                              // span length prefix

    const int tid = threadIdx.x;
    const int p = tid >> 6;              // wave 0..7
    const int lane = tid & 63;

    const float ell = expf(log_ell[0]);
    const float cmag = 0.5f / (ell * ell) * 1.4426950408889634f;
    const bool fb = (TCUT / cmag) > (4.0f * H * H);   // r_cut > 2h

    float4 tp = T4[tw * 64 + lane];
    const float x = tp.x, y = tp.y, b = tp.z;
    const int oi = __float_as_int(tp.w);              // valid iff >= 1

    if (tid == 0) {
        if (fb) {
            sS[0] = 0; sP[0] = 0;
            int tot = hdr[1];
            sP[1] = tot;
            for (int r = 1; r < 5; ++r) { sS[r] = 0; sP[r + 1] = tot; }
        } else {
            // lane 0 of wave 0 is always a real point (pads go at cell tails)
            int cx = cellco(x), cy = cellco(y);
            int pre = 0;
            for (int r = 0; r < 5; ++r) {
                int ty = cy + r - 2;
                int s = 0, l = 0;
                if (ty >= 0 && ty < NC) {
                    int cl = ty * NC + max(0, cx - 2);
                    int cr = ty * NC + min(NC - 1, cx + 2);
                    s = trs4[cl];
                    l = trs4[cr + 1] - s;
                }
                sS[r] = s; sP[r] = pre; pre += l;
            }
            sP[5] = pre;
        }
    }
    __syncthreads();
    const int total = sP[5];             // multiple of 4 by construction

    float a0 = 0.f, a1 = 0.f;
    for (int base = 0; base < total; base += CHUNK) {
        const int n = min(CHUNK, total - base);
        __syncthreads();                 // prev chunk fully consumed
        for (int g = tid; g < n; g += 512) {
            int gg = base + g;
            int r = 0;
            while (r < 4 && gg >= sP[r + 1]) ++r;
            int j = sS[r] + (gg - sP[r]);
            float4 tv = trA[j];
            float w1 = trW1[j];
            // scrub pad slots holding non-real data (poison/zero are already
            // numerically harmless; this guards NaN/huge garbage too)
            if (!(tv.z >= -1.0e6f && tv.z <= 0.f)) {
                tv.z = -1.0e30f; tv.w = 0.f; w1 = 0.f;
            }
            sA[g] = tv;
            sW[g] = w1;
        }
        __syncthreads();
        const int nq = n >> 2;
#pragma unroll 2
        for (int q = p; q < nq; q += 8) {
            float4 t0 = sA[4 * q];
            float4 t1 = sA[4 * q + 1];
            float4 t2 = sA[4 * q + 2];
            float4 t3 = sA[4 * q + 3];
            float4 wv = *(const float4*)&sW[4 * q];
            float e0 = fexp2(fmaf(t0.x, x, fmaf(t0.y, y, b + t0.z)));
            float e1 = fexp2(fmaf(t1.x, x, fmaf(t1.y, y, b + t1.z)));
            float e2 = fexp2(fmaf(t2.x, x, fmaf(t2.y, y, b + t2.z)));
            float e3 = fexp2(fmaf(t3.x, x, fmaf(t3.y, y, b + t3.z)));
            a0 = fmaf(e0, t0.w, a0); a1 = fmaf(e0, wv.x, a1);
            a0 = fmaf(e1, t1.w, a0); a1 = fmaf(e1, wv.y, a1);
            a0 = fmaf(e2, t2.w, a0); a1 = fmaf(e2, wv.z, a1);
            a0 = fmaf(e3, t3.w, a0); a1 = fmaf(e3, wv.w, a1);
        }
    }

    red[p][lane] = make_float2(a0, a1);
    __syncthreads();
    if (p == 0) {
        float s0 = 0.f, s1 = 0.f;
#pragma unroll
        for (int q = 0; q < 8; ++q) {
            float2 v = red[q][lane];
            s0 += v.x; s1 += v.y;
        }
        if (oi >= 1)
            out2[oi - 1] = make_float2(s0, s1);
    }
}

// --- dense fallback (ws too small) ------------------------------------------
__global__ __launch_bounds__(256, 8) void gp_dense(
        const float2* __restrict__ Xte, const float2* __restrict__ Xtr,
        const float2* __restrict__ alpha, const float* __restrict__ log_ell,
        const float* __restrict__ log_sf, float* __restrict__ out) {
    __shared__ float4 sSt[128];
    __shared__ float sA1[128];
    const int tid = threadIdx.x;
    const float ell = expf(log_ell[0]);
    const float c = -0.5f / (ell * ell) * 1.4426950408889634f;
    const int j0 = blockIdx.y * 128;
    if (tid < 128) {
        const float sf2 = expf(2.0f * log_sf[0]);
        float2 t = Xtr[j0 + tid];
        float2 a = alpha[j0 + tid];
        sSt[tid] = make_float4(-2.f * c * t.x, -2.f * c * t.y,
                               c * (t.x * t.x + t.y * t.y), sf2 * a.x);
        sA1[tid] = sf2 * a.y;
    }
    const int base = blockIdx.x * 1024 + tid;
    float2 x0 = Xte[base], x1 = Xte[base + 256];
    float2 x2 = Xte[base + 512], x3 = Xte[base + 768];
    const float b0 = c * (x0.x * x0.x + x0.y * x0.y);
    const float b1 = c * (x1.x * x1.x + x1.y * x1.y);
    const float b2 = c * (x2.x * x2.x + x2.y * x2.y);
    const float b3 = c * (x3.x * x3.x + x3.y * x3.y);
    __syncthreads();
    float a00 = 0.f, a01 = 0.f, a10 = 0.f, a11 = 0.f;
    float a20 = 0.f, a21 = 0.f, a30 = 0.f, a31 = 0.f;
#pragma unroll 2
    for (int j = 0; j < 128; ++j) {
        float4 s = sSt[j];
        float w1 = sA1[j];
        float e0 = fexp2(fminf(fmaf(s.x, x0.x, fmaf(s.y, x0.y, b0 + s.z)), 0.f));
        float e1 = fexp2(fminf(fmaf(s.x, x1.x, fmaf(s.y, x1.y, b1 + s.z)), 0.f));
        float e2 = fexp2(fminf(fmaf(s.x, x2.x, fmaf(s.y, x2.y, b2 + s.z)), 0.f));
        float e3 = fexp2(fminf(fmaf(s.x, x3.x, fmaf(s.y, x3.y, b3 + s.z)), 0.f));
        a00 = fmaf(e0, s.w, a00); a01 = fmaf(e0, w1, a01);
        a10 = fmaf(e1, s.w, a10); a11 = fmaf(e1, w1, a11);
        a20 = fmaf(e2, s.w, a20); a21 = fmaf(e2, w1, a21);
        a30 = fmaf(e3, s.w, a30); a31 = fmaf(e3, w1, a31);
    }
    gatomic_fadd(&out[2 * base], a00);            gatomic_fadd(&out[2 * base + 1], a01);
    gatomic_fadd(&out[2 * (base + 256)], a10);    gatomic_fadd(&out[2 * (base + 256) + 1], a11);
    gatomic_fadd(&out[2 * (base + 512)], a20);    gatomic_fadd(&out[2 * (base + 512) + 1], a21);
    gatomic_fadd(&out[2 * (base + 768)], a30);    gatomic_fadd(&out[2 * (base + 768) + 1], a31);
}

extern "C" void kernel_launch(void* const* d_in, const int* in_sizes, int n_in,
                              void* d_out, int out_size, void* d_ws, size_t ws_size,
                              hipStream_t stream) {
    const float2* Xte = (const float2*)d_in[0];
    const float2* Xtr = (const float2*)d_in[1];
    const float2* alpha = (const float2*)d_in[2];
    const float* log_ell = (const float*)d_in[3];
    const float* log_sf = (const float*)d_in[4];
    float* out = (float*)d_out;

    if (ws_size >= WS_NEED) {
        char* ws = (char*)d_ws;
        int* hdr = (int*)(ws + OFF_HDR);
        int* trs4 = (int*)(ws + OFF_TRS4);
        int* trcur = (int*)(ws + OFF_TRCUR);
        int* tecur = (int*)(ws + OFF_TECUR);
        float4* trA = (float4*)(ws + OFF_TRA);
        float* trW1 = (float*)(ws + OFF_TRW1);
        float4* T4 = (float4*)(ws + OFF_T4);

        hist_scan_kernel<<<1, 1024, 0, stream>>>(Xtr, Xte, trs4, trcur, tecur, hdr);
        scatter_kernel<<<N_PTS / 256, 256, 0, stream>>>(
            Xtr, Xte, alpha, log_ell, log_sf, trcur, tecur, trA, trW1, T4);
        gp_main<<<MAXWAVES, 512, 0, stream>>>(T4, trA, trW1, trs4, hdr, log_ell,
                                              (float2*)out);
    } else {
        hipMemsetAsync(out, 0, (size_t)out_size * sizeof(float), stream);
        dim3 grid(M_PTS / 1024, N_PTS / 128);
        gp_dense<<<grid, 256, 0, stream>>>(Xte, Xtr, alpha, log_ell, log_sf, out);
    }
}

// Round 6
// 115.652 us; speedup vs baseline: 1.7907x; 1.1273x over previous
//
#include <hip/hip_runtime.h>
#include <math.h>

// Problem constants (fixed by the reference).
#define M_PTS 16384
#define N_PTS 16384

// Spatial binning: 42x42 cells of h=0.25 over [-5.25, 5.25).
// Drop terms with exp2(arg) < 2^-TCUT <=> sq > TCUT/cmag (r_cut^2).
// ell=0.1 -> cmag=72.13 -> r_cut=0.527 -> K=3 rows, disc-shaped col ranges.
// Planner falls back to full scans if ell too large for the grid.
#define NC 42
#define NCELLS (NC * NC)          // 1764
#define NPAIR (NCELLS / 2)        // 882
#define H 0.25f
#define INV_H 4.0f
#define ORIG (-5.25f)
#define TCUT 20.0f
#define KMAX 7
#define MAXROWS 16
#define NWAVES (M_PTS / 64)       // 256 test waves (no padding; M = 256*64)
#define CHUNK 1024
#define MAX_ITEMS 4096            // >= NWAVES * ceil(N_PTS/CHUNK)

// ws byte offsets
#define OFF_NITEMS 0
#define OFF_TRCUR 64
#define OFF_TECUR (OFF_TRCUR + NCELLS * 4)
#define OFF_SROW  (OFF_TECUR + NCELLS * 4)            // int[NWAVES*16]
#define OFF_SPRE  (OFF_SROW + NWAVES * MAXROWS * 4)   // int[NWAVES*17]
#define OFF_ITEMS (OFF_SPRE + NWAVES * (MAXROWS + 1) * 4)
#define OFF_TRA   ((OFF_ITEMS + MAX_ITEMS * 4 + 255) & ~255)
#define OFF_TRW1  (OFF_TRA + N_PTS * 16)
#define OFF_T4    (OFF_TRW1 + N_PTS * 4)
#define WS_NEED   (OFF_T4 + (size_t)M_PTS * 16)       // ~640 KB

__device__ __forceinline__ float fexp2(float x) {
#if __has_builtin(__builtin_amdgcn_exp2f)
    return __builtin_amdgcn_exp2f(x);
#else
    return exp2f(x);
#endif
}

__device__ __forceinline__ void gatomic_fadd(float* p, float v) {
    asm volatile("global_atomic_add_f32 %0, %1, off" :: "v"(p), "v"(v) : "memory");
}

__device__ __forceinline__ int cellco(float v) {
    int c = (int)floorf((v - ORIG) * INV_H);
    return min(NC - 1, max(0, c));
}

// --- d1: histogram + scans + per-wave window planning, one block -------------
__global__ __launch_bounds__(1024) void prep_kernel(
        const float2* __restrict__ Xtr, const float2* __restrict__ Xte,
        const float* __restrict__ log_ell,
        int* __restrict__ trcur, int* __restrict__ tecur,
        int* __restrict__ sRowG, int* __restrict__ sPreG,
        int* __restrict__ items, int* __restrict__ nitemsG) {
    __shared__ int hTr[NCELLS], hTe[NCELLS];
    __shared__ int sc[1024];
    __shared__ int trsL[NCELLS + 1], PL[NCELLS + 1];
    const int tid = threadIdx.x;

    if (tid == 0) nitemsG[0] = 0;
    for (int i = tid; i < NCELLS; i += 1024) { hTr[i] = 0; hTe[i] = 0; }
    __syncthreads();
    for (int i = tid; i < N_PTS; i += 1024) {
        float2 t = Xtr[i];
        atomicAdd(&hTr[cellco(t.y) * NC + cellco(t.x)], 1);
        float2 x = Xte[i];
        atomicAdd(&hTe[cellco(x.y) * NC + cellco(x.x)], 1);
    }
    __syncthreads();

    // scan train counts (pairwise: 1764 = 2*882)
    int pv = (tid < NPAIR) ? (hTr[2 * tid] + hTr[2 * tid + 1]) : 0;
    sc[tid] = pv; __syncthreads();
    for (int off = 1; off < 1024; off <<= 1) {
        int u = (tid >= off) ? sc[tid - off] : 0;
        __syncthreads(); sc[tid] += u; __syncthreads();
    }
    if (tid < NPAIR) {
        int e = sc[tid] - pv;
        trsL[2 * tid] = e;
        trsL[2 * tid + 1] = e + hTr[2 * tid];
    }
    if (tid == NPAIR - 1) trsL[NCELLS] = sc[tid];
    __syncthreads();

    // scan test counts
    pv = (tid < NPAIR) ? (hTe[2 * tid] + hTe[2 * tid + 1]) : 0;
    sc[tid] = pv; __syncthreads();
    for (int off = 1; off < 1024; off <<= 1) {
        int u = (tid >= off) ? sc[tid - off] : 0;
        __syncthreads(); sc[tid] += u; __syncthreads();
    }
    if (tid < NPAIR) {
        int e = sc[tid] - pv;
        PL[2 * tid] = e;
        PL[2 * tid + 1] = e + hTe[2 * tid];
    }
    if (tid == NPAIR - 1) PL[NCELLS] = sc[tid];
    __syncthreads();

    for (int c = tid; c < NCELLS; c += 1024) {
        trcur[c] = trsL[c];
        tecur[c] = PL[c];
    }

    // planner: one thread per test wave of 64 consecutive sorted points
    if (tid < NWAVES) {
        const int w = tid;
        const float ell = expf(log_ell[0]);
        const float cmag = 0.5f / (ell * ell) * 1.4426950408889634f;
        const float r2 = TCUT / cmag;
        const int K = (int)floorf(sqrtf(r2) * INV_H) + 1;

        // cells containing sorted test positions 64w and 64w+63
        int clo, chi;
        {
            int s = w * 64, lo = 0, hi = NCELLS;
            while (lo + 1 < hi) { int m = (lo + hi) >> 1; if (PL[m] <= s) lo = m; else hi = m; }
            clo = lo;
            s = w * 64 + 63; lo = 0; hi = NCELLS;
            while (lo + 1 < hi) { int m = (lo + hi) >> 1; if (PL[m] <= s) lo = m; else hi = m; }
            chi = lo;
        }
        const int rl = clo / NC, cl = clo % NC;
        const int rh = chi / NC, ch = chi % NC;
        int wlo = max(0, rl - K), whi = min(NC - 1, rh + K);
        int nr = whi - wlo + 1;
        bool full = (K > KMAX) || (nr > MAXROWS);

        int pre = 0;
        if (full) {
            sRowG[w * MAXROWS] = 0;
            sPreG[w * (MAXROWS + 1)] = 0;
            pre = N_PTS;
            for (int i = 1; i <= MAXROWS; ++i) sPreG[w * (MAXROWS + 1) + i] = N_PTS;
        } else {
            const bool single = (rl == rh);
            const int cmin = single ? cl : 0;
            const int cmax = single ? ch : (NC - 1);
            sPreG[w * (MAXROWS + 1)] = 0;
            int idx = 0;
            for (int wr = wlo; wr <= whi; ++wr, ++idx) {
                int dy = (wr < rl) ? (rl - wr) : ((wr > rh) ? (wr - rh) : 0);
                int kx;
                if (dy <= 1) kx = K;
                else {
                    float d = (float)(dy - 1) * H;
                    kx = (int)floorf(sqrtf(fmaxf(r2 - d * d, 0.f)) * INV_H) + 1;
                }
                int c0 = max(0, cmin - kx);
                int c1 = min(NC - 1, cmax + kx);
                int js = trsL[wr * NC + c0];
                int je = trsL[wr * NC + c1 + 1];
                sRowG[w * MAXROWS + idx] = js - pre;   // j = gg + offset
                pre += je - js;
                sPreG[w * (MAXROWS + 1) + idx + 1] = pre;
            }
            for (; idx < MAXROWS; ++idx)
                sPreG[w * (MAXROWS + 1) + idx + 1] = pre;
        }
        const int nch = (pre + CHUNK - 1) / CHUNK;
        for (int k = 0; k < nch; ++k) {
            int slot = atomicAdd(nitemsG, 1);
            items[slot] = w | (k << 16);
        }
    }
}

// --- d2: scatter sorted/staged data + zero out -------------------------------
// trA[p] = (-2c*t0, -2c*t1, c*|t|^2, sf2*a0), trW1[p] = sf2*a1.
// T4[p] = (x, y, c*|x|^2, orig idx bits). No padding anywhere.
__global__ void scatter_kernel(const float2* __restrict__ Xtr,
                               const float2* __restrict__ Xte,
                               const float2* __restrict__ alpha,
                               const float* __restrict__ log_ell,
                               const float* __restrict__ log_sf,
                               int* __restrict__ trcur, int* __restrict__ tecur,
                               float4* __restrict__ trA, float* __restrict__ trW1,
                               float4* __restrict__ T4, float2* __restrict__ out2) {
    int i = blockIdx.x * blockDim.x + threadIdx.x;
    if (i >= N_PTS) return;
    out2[i] = make_float2(0.f, 0.f);
    float ell = expf(log_ell[0]);
    float sf2 = expf(2.0f * log_sf[0]);
    float c = -0.5f / (ell * ell) * 1.4426950408889634f;  // * log2(e), c < 0

    float2 t = Xtr[i];
    float2 a = alpha[i];
    int ct = cellco(t.y) * NC + cellco(t.x);
    int pt = atomicAdd(&trcur[ct], 1);
    trA[pt] = make_float4(-2.f * c * t.x, -2.f * c * t.y,
                          c * (t.x * t.x + t.y * t.y), sf2 * a.x);
    trW1[pt] = sf2 * a.y;

    float2 x = Xte[i];
    int cx = cellco(x.y) * NC + cellco(x.x);
    int px = atomicAdd(&tecur[cx], 1);
    T4[px] = make_float4(x.x, x.y, c * (x.x * x.x + x.y * x.y),
                         __int_as_float(i));
}

// --- d3: main kernel ---------------------------------------------------------
// Item = (test-wave w, 1024-train chunk k of w's window). Block = 256 threads
// = 4 waves, all holding the same 64 test points; stage the chunk to LDS
// (coalesced, via per-row offset table), 4 waves split the quads, LDS-reduce,
// atomicAdd 2 floats per lane. Dummy pad slots underflow in exp2 (weight 0).
__global__ __launch_bounds__(256) void gp_main(
        const float4* __restrict__ T4, const float4* __restrict__ trA,
        const float* __restrict__ trW1, const int* __restrict__ sRowG,
        const int* __restrict__ sPreG, const int* __restrict__ items,
        const int* __restrict__ nitemsG, float* __restrict__ out) {
    const int nit = nitemsG[0];
    if ((int)blockIdx.x >= nit) return;
    const int item = items[blockIdx.x];
    const int w = item & 0xFFFF;
    const int k = item >> 16;

    __shared__ float4 sA[CHUNK];                     // 16 KB
    __shared__ __align__(16) float sW[CHUNK];        // 4 KB
    __shared__ float2 red[4][64];                    // 2 KB
    __shared__ int off[MAXROWS];
    __shared__ int pre[MAXROWS + 1];

    const int tid = threadIdx.x;
    const int p = tid >> 6;          // wave 0..3
    const int lane = tid & 63;

    if (tid < MAXROWS) off[tid] = sRowG[w * MAXROWS + tid];
    if (tid < MAXROWS + 1) pre[tid] = sPreG[w * (MAXROWS + 1) + tid];

    float4 tp = T4[w * 64 + lane];
    const float x = tp.x, y = tp.y, b = tp.z;
    const int oi = __float_as_int(tp.w);
    __syncthreads();

    const int total = pre[MAXROWS];
    const int base0 = k << 10;
    const int n = min(CHUNK, total - base0);

    // stage: persistent row cursor (gg monotone across the strided loop)
    {
        int r = 0;
        for (int g = tid; g < CHUNK; g += 256) {
            float4 tv; float wv;
            if (g < n) {
                int gg = base0 + g;
                while (gg >= pre[r + 1]) ++r;
                int j = gg + off[r];
                tv = trA[j];
                wv = trW1[j];
            } else {
                tv = make_float4(0.f, 0.f, -1.0e30f, 0.f);
                wv = 0.f;
            }
            sA[g] = tv;
            sW[g] = wv;
        }
    }
    __syncthreads();

    float a0 = 0.f, a1 = 0.f;
#pragma unroll 2
    for (int q = p; q < CHUNK / 4; q += 4) {
        float4 t0 = sA[4 * q];
        float4 t1 = sA[4 * q + 1];
        float4 t2 = sA[4 * q + 2];
        float4 t3 = sA[4 * q + 3];
        float4 wv = *(const float4*)&sW[4 * q];
        float e0 = fexp2(fmaf(t0.x, x, fmaf(t0.y, y, b + t0.z)));
        float e1 = fexp2(fmaf(t1.x, x, fmaf(t1.y, y, b + t1.z)));
        float e2 = fexp2(fmaf(t2.x, x, fmaf(t2.y, y, b + t2.z)));
        float e3 = fexp2(fmaf(t3.x, x, fmaf(t3.y, y, b + t3.z)));
        a0 = fmaf(e0, t0.w, a0); a1 = fmaf(e0, wv.x, a1);
        a0 = fmaf(e1, t1.w, a0); a1 = fmaf(e1, wv.y, a1);
        a0 = fmaf(e2, t2.w, a0); a1 = fmaf(e2, wv.z, a1);
        a0 = fmaf(e3, t3.w, a0); a1 = fmaf(e3, wv.w, a1);
    }

    red[p][lane] = make_float2(a0, a1);
    __syncthreads();
    if (p == 0) {
        float s0 = 0.f, s1 = 0.f;
#pragma unroll
        for (int q = 0; q < 4; ++q) {
            float2 v = red[q][lane];
            s0 += v.x; s1 += v.y;
        }
        if (s0 != 0.f || s1 != 0.f) {
            gatomic_fadd(&out[2 * oi], s0);
            gatomic_fadd(&out[2 * oi + 1], s1);
        }
    }
}

// --- dense fallback (ws too small) ------------------------------------------
__global__ __launch_bounds__(256, 8) void gp_dense(
        const float2* __restrict__ Xte, const float2* __restrict__ Xtr,
        const float2* __restrict__ alpha, const float* __restrict__ log_ell,
        const float* __restrict__ log_sf, float* __restrict__ out) {
    __shared__ float4 sSt[128];
    __shared__ float sA1[128];
    const int tid = threadIdx.x;
    const float ell = expf(log_ell[0]);
    const float c = -0.5f / (ell * ell) * 1.4426950408889634f;
    const int j0 = blockIdx.y * 128;
    if (tid < 128) {
        const float sf2 = expf(2.0f * log_sf[0]);
        float2 t = Xtr[j0 + tid];
        float2 a = alpha[j0 + tid];
        sSt[tid] = make_float4(-2.f * c * t.x, -2.f * c * t.y,
                               c * (t.x * t.x + t.y * t.y), sf2 * a.x);
        sA1[tid] = sf2 * a.y;
    }
    const int base = blockIdx.x * 1024 + tid;
    float2 x0 = Xte[base], x1 = Xte[base + 256];
    float2 x2 = Xte[base + 512], x3 = Xte[base + 768];
    const float b0 = c * (x0.x * x0.x + x0.y * x0.y);
    const float b1 = c * (x1.x * x1.x + x1.y * x1.y);
    const float b2 = c * (x2.x * x2.x + x2.y * x2.y);
    const float b3 = c * (x3.x * x3.x + x3.y * x3.y);
    __syncthreads();
    float a00 = 0.f, a01 = 0.f, a10 = 0.f, a11 = 0.f;
    float a20 = 0.f, a21 = 0.f, a30 = 0.f, a31 = 0.f;
#pragma unroll 2
    for (int j = 0; j < 128; ++j) {
        float4 s = sSt[j];
        float w1 = sA1[j];
        float e0 = fexp2(fminf(fmaf(s.x, x0.x, fmaf(s.y, x0.y, b0 + s.z)), 0.f));
        float e1 = fexp2(fminf(fmaf(s.x, x1.x, fmaf(s.y, x1.y, b1 + s.z)), 0.f));
        float e2 = fexp2(fminf(fmaf(s.x, x2.x, fmaf(s.y, x2.y, b2 + s.z)), 0.f));
        float e3 = fexp2(fminf(fmaf(s.x, x3.x, fmaf(s.y, x3.y, b3 + s.z)), 0.f));
        a00 = fmaf(e0, s.w, a00); a01 = fmaf(e0, w1, a01);
        a10 = fmaf(e1, s.w, a10); a11 = fmaf(e1, w1, a11);
        a20 = fmaf(e2, s.w, a20); a21 = fmaf(e2, w1, a21);
        a30 = fmaf(e3, s.w, a30); a31 = fmaf(e3, w1, a31);
    }
    gatomic_fadd(&out[2 * base], a00);            gatomic_fadd(&out[2 * base + 1], a01);
    gatomic_fadd(&out[2 * (base + 256)], a10);    gatomic_fadd(&out[2 * (base + 256) + 1], a11);
    gatomic_fadd(&out[2 * (base + 512)], a20);    gatomic_fadd(&out[2 * (base + 512) + 1], a21);
    gatomic_fadd(&out[2 * (base + 768)], a30);    gatomic_fadd(&out[2 * (base + 768) + 1], a31);
}

extern "C" void kernel_launch(void* const* d_in, const int* in_sizes, int n_in,
                              void* d_out, int out_size, void* d_ws, size_t ws_size,
                              hipStream_t stream) {
    const float2* Xte = (const float2*)d_in[0];
    const float2* Xtr = (const float2*)d_in[1];
    const float2* alpha = (const float2*)d_in[2];
    const float* log_ell = (const float*)d_in[3];
    const float* log_sf = (const float*)d_in[4];
    float* out = (float*)d_out;

    if (ws_size >= WS_NEED) {
        char* ws = (char*)d_ws;
        int* nitems = (int*)(ws + OFF_NITEMS);
        int* trcur = (int*)(ws + OFF_TRCUR);
        int* tecur = (int*)(ws + OFF_TECUR);
        int* sRowG = (int*)(ws + OFF_SROW);
        int* sPreG = (int*)(ws + OFF_SPRE);
        int* items = (int*)(ws + OFF_ITEMS);
        float4* trA = (float4*)(ws + OFF_TRA);
        float* trW1 = (float*)(ws + OFF_TRW1);
        float4* T4 = (float4*)(ws + OFF_T4);

        prep_kernel<<<1, 1024, 0, stream>>>(Xtr, Xte, log_ell, trcur, tecur,
                                            sRowG, sPreG, items, nitems);
        scatter_kernel<<<N_PTS / 256, 256, 0, stream>>>(
            Xtr, Xte, alpha, log_ell, log_sf, trcur, tecur, trA, trW1, T4,
            (float2*)out);
        gp_main<<<MAX_ITEMS, 256, 0, stream>>>(T4, trA, trW1, sRowG, sPreG,
                                               items, nitems, out);
    } else {
        hipMemsetAsync(out, 0, (size_t)out_size * sizeof(float), stream);
        dim3 grid(M_PTS / 1024, N_PTS / 128);
        gp_dense<<<grid, 256, 0, stream>>>(Xte, Xtr, alpha, log_ell, log_sf, out);
    }
}